// Round 4
// baseline (72.932 us; speedup 1.0000x reference)
//
#include <hip/hip_runtime.h>

// SoftGraphCut: solve (I + weighted 5-point graph Laplacian) x = b on a 64x64
// grid; 4 batches x 21 channels = 84 independent RHS (matrix shared per batch).
//
// Algorithm: Chebyshev semi-iteration on the Jacobi-scaled operator
// A_hat = D^-1 A (diag == 1). Gershgorin: s = sum of <=4 U[0,1) weights < 4
// => spectrum of A_hat in [1 - s/(1+s), 1 + s/(1+s)] subset [0.2, 1.8].
// Fixed interval => all coefficients compile-time, ZERO inner products,
// guaranteed factor 0.5/iter; 32 iters -> 2*0.5^32 ~ 5e-10 energy-norm
// reduction: fully stagnated at the fp32 rounding floor (same floor as the
// fp32 LU reference).
//
// Formulation tracks the PRECONDITIONED residual rr = D^-1 (b - A x):
//   rr_{k+1} = rr_k - A_hat d_k = rr_k - d + sum(chat_* . neighbor)
// with chat_* = w_* / K baked into the setup -> 8 VALU ops/point/iter
// (1 sub + 4 fma for rr, 1 add for x, 1 mul + 1 fma for d). No separate
// z = D^-1 r step.
//
// Structure: 1 block per (batch,channel) = 84 blocks x 512 threads; thread
// owns a 2-row x 4-col patch. d double-buffered in LDS at stride 64
// (16B-aligned ds_read/write_b128, coalesced). Vertical in-pair neighbor
// in-register; horizontal neighbors via __shfl lane+-1 (wrap garbage only
// where the boundary coefficient is exactly 0). One barrier per iteration.
// NOTE: stencil consumes only OLD d values; new values go to nd[][] and are
// copied after the k-loop (in-place update would corrupt left-neighbors).

#define GH 64
#define GW 64
#define GM 4096
#define NTH 512
#define NITER 32

struct ChebC { float c1[NITER]; float c2[NITER]; };
constexpr ChebC make_cheb() {
    // theta = 1.0, delta = 0.8, sigma = theta/delta = 1.25 (Saad Alg. 12.1)
    ChebC c{};
    float rho = 0.8f;                            // rho_0 = 1/sigma
    for (int k = 0; k < NITER; ++k) {
        const float rho_n = 1.0f / (2.5f - rho); // rho_{k+1} = 1/(2 sigma - rho_k)
        c.c1[k] = rho_n * rho;                   // d_{k+1} = c1*d_k + c2*rr_{k+1}
        c.c2[k] = 2.0f * rho_n / 0.8f;
        rho = rho_n;
    }
    return c;
}
constexpr ChebC CHEB = make_cheb();

__global__ __launch_bounds__(NTH) void sgc_cheb_kernel(
    const float* __restrict__ scores,   // [4,21,64,64]
    const float* __restrict__ wcol,     // [4,63,64]
    const float* __restrict__ wrow,     // [4,64,63]
    float* __restrict__ out)            // [4,21,64,64]
{
    const int blk  = blockIdx.x;             // 0..83
    const int b    = blk / 21;
    const int ch   = blk - b * 21;
    const int t    = threadIdx.x;
    const int lane = t & 63;
    const int R    = t >> 4;                 // rowpair 0..31
    const int rT   = R << 1;                 // top row of pair
    const int rB   = rT + 1;                 // bottom row of pair
    const int col0 = (t & 15) << 2;          // first owned column

    __shared__ float dbuf[2][GH][GW];        // 32 KB, stride 64 -> b128 aligned

    const float* wc = wcol + b * (63 * 64);
    const float* wr = wrow + b * (64 * 63);
    const float* bv = scores + (size_t)(b * 21 + ch) * GM;
    float*       ov = out    + (size_t)(b * 21 + ch) * GM;

    const int rowu = (rT > 0)  ? rT - 1 : 0; // halo row above (coef 0 at edge)
    const int rowd = (rB < 63) ? rB + 1 : 63;

    // Scaled stencil coefficients (reference A, then divided by diag K):
    // A[p,p]    = 1 + wc[i-1,j] + wc[i,j] + wr[i,j-1] + wr[i,j] = K
    // A[p,p-64] = -wc[i-1,j]  A[p,p+64] = -wc[i,j]
    // A[p,p-1]  = -wr[i,j-1]  A[p,p+1]  = -wr[i,j]
    // A_hat row p: 1 on diag, -w_*/K off-diag.
    float hU[2][4], hD[2][4], hL[2][4], hR[2][4], iK[2][4];
#pragma unroll
    for (int rr_ = 0; rr_ < 2; ++rr_) {
        const int i = rT + rr_;
#pragma unroll
        for (int k = 0; k < 4; ++k) {
            const int j = col0 + k;
            const float u  = (i > 0)  ? wc[(i - 1) * 64 + j] : 0.f;
            const float dn = (i < 63) ? wc[i * 64 + j]       : 0.f;
            const float l  = (j > 0)  ? wr[i * 63 + (j - 1)] : 0.f;
            const float rg = (j < 63) ? wr[i * 63 + j]       : 0.f;
            const float ik = 1.f / (1.f + u + dn + l + rg);
            iK[rr_][k] = ik;
            hU[rr_][k] = u  * ik;
            hD[rr_][k] = dn * ik;
            hL[rr_][k] = l  * ik;
            hR[rr_][k] = rg * ik;
        }
    }

    // init: x = 0, rr = D^-1 b, d = rr/theta = rr (theta = 1)
    float x[2][4], rr[2][4], d[2][4];
    const float4 bT = *reinterpret_cast<const float4*>(bv + rT * 64 + col0);
    const float4 bB = *reinterpret_cast<const float4*>(bv + rB * 64 + col0);
    const float bbT[4] = {bT.x, bT.y, bT.z, bT.w};
    const float bbB[4] = {bB.x, bB.y, bB.z, bB.w};
#pragma unroll
    for (int k = 0; k < 4; ++k) {
        x[0][k] = 0.f;  x[1][k] = 0.f;
        rr[0][k] = bbT[k] * iK[0][k];
        rr[1][k] = bbB[k] * iK[1][k];
        d[0][k] = rr[0][k];
        d[1][k] = rr[1][k];
    }
    *reinterpret_cast<float4*>(&dbuf[0][rT][col0]) =
        make_float4(d[0][0], d[0][1], d[0][2], d[0][3]);
    *reinterpret_cast<float4*>(&dbuf[0][rB][col0]) =
        make_float4(d[1][0], d[1][1], d[1][2], d[1][3]);
    __syncthreads();

    const int laneL = (lane + 63) & 63;
    const int laneR = (lane + 1) & 63;

#pragma unroll
    for (int it = 0; it < NITER; ++it) {
        const float (*rd)[GW] = dbuf[it & 1];
        float      (*wrt)[GW] = dbuf[(it + 1) & 1];

        // halo rows (neighbor rowpairs' published OLD d)
        const float4 pu4 = *reinterpret_cast<const float4*>(&rd[rowu][col0]);
        const float4 pd4 = *reinterpret_cast<const float4*>(&rd[rowd][col0]);
        const float pu[4] = {pu4.x, pu4.y, pu4.z, pu4.w};
        const float pd[4] = {pd4.x, pd4.y, pd4.z, pd4.w};

        // horizontal neighbors across lanes (wrap garbage x coef 0 at edges)
        const float plT = __shfl(d[0][3], laneL, 64);
        const float plB = __shfl(d[1][3], laneL, 64);
        const float prT = __shfl(d[0][0], laneR, 64);
        const float prB = __shfl(d[1][0], laneR, 64);

        // x += d; rr = rr - d + sum(h_* . neighbor); nd = c1*d + c2*rr
        float nd[2][4];
#pragma unroll
        for (int k = 0; k < 4; ++k) {
            const float cT = d[0][k];
            const float cB = d[1][k];
            const float lT = (k == 0) ? plT : d[0][k - 1];   // OLD d only
            const float lB = (k == 0) ? plB : d[1][k - 1];
            const float gT = (k == 3) ? prT : d[0][k + 1];
            const float gB = (k == 3) ? prB : d[1][k + 1];

            float rT_ = rr[0][k] - cT;
            rT_ = fmaf(hU[0][k], pu[k], rT_);
            rT_ = fmaf(hD[0][k], cB,   rT_);
            rT_ = fmaf(hL[0][k], lT,   rT_);
            rT_ = fmaf(hR[0][k], gT,   rT_);

            float rB_ = rr[1][k] - cB;
            rB_ = fmaf(hU[1][k], cT,   rB_);
            rB_ = fmaf(hD[1][k], pd[k], rB_);
            rB_ = fmaf(hL[1][k], lB,   rB_);
            rB_ = fmaf(hR[1][k], gB,   rB_);

            x[0][k] += cT;
            x[1][k] += cB;
            rr[0][k] = rT_;
            rr[1][k] = rB_;
            nd[0][k] = CHEB.c1[it] * cT + CHEB.c2[it] * rT_;
            nd[1][k] = CHEB.c1[it] * cB + CHEB.c2[it] * rB_;
        }
#pragma unroll
        for (int k = 0; k < 4; ++k) {        // commit after all old-d reads
            d[0][k] = nd[0][k];
            d[1][k] = nd[1][k];
        }

        *reinterpret_cast<float4*>(&wrt[rT][col0]) =
            make_float4(d[0][0], d[0][1], d[0][2], d[0][3]);
        *reinterpret_cast<float4*>(&wrt[rB][col0]) =
            make_float4(d[1][0], d[1][1], d[1][2], d[1][3]);
        __syncthreads();   // publish d_{it+1}; all reads of rd finished above
    }

    *reinterpret_cast<float4*>(ov + rT * 64 + col0) =
        make_float4(x[0][0], x[0][1], x[0][2], x[0][3]);
    *reinterpret_cast<float4*>(ov + rB * 64 + col0) =
        make_float4(x[1][0], x[1][1], x[1][2], x[1][3]);
}

extern "C" void kernel_launch(void* const* d_in, const int* in_sizes, int n_in,
                              void* d_out, int out_size, void* d_ws, size_t ws_size,
                              hipStream_t stream) {
    const float* scores = (const float*)d_in[0];  // [4,21,64,64]
    const float* wcol   = (const float*)d_in[1];  // [4,63,64]
    const float* wrow   = (const float*)d_in[2];  // [4,64,63]
    float* out = (float*)d_out;

    sgc_cheb_kernel<<<84, NTH, 0, stream>>>(scores, wcol, wrow, out);
}

// Round 5
// 68.314 us; speedup vs baseline: 1.0676x; 1.0676x over previous
//
#include <hip/hip_runtime.h>

// SoftGraphCut: solve (I + weighted 5-point graph Laplacian) x = b on a 64x64
// grid; 4 batches x 21 channels = 84 independent RHS (matrix shared per batch).
//
// Algorithm: Chebyshev semi-iteration on the Jacobi-scaled operator
// A_hat = D^-1 A (diag == 1). Gershgorin: s = sum of <=4 U[0,1) weights < 4
// => spectrum of A_hat in [1 - s/(1+s), 1 + s/(1+s)] subset [0.2, 1.8].
// Fixed interval => all coefficients compile-time, ZERO inner products,
// guaranteed factor rho = (sqrt(9)-1)/(sqrt(9)+1) = 0.5 per iter.
// NITER=20: ||e||_A <= 2*0.5^20 * ||x*||_A <= 2e-6 * 64 ~ 1.2e-4 absolute --
// far below the fp32 dense-LU reference's own rounding floor (~4e-3 at
// n=4096, observed absmax 0.0039 in round 4 = reference-dominated).
//
// Formulation tracks the PRECONDITIONED residual rr = D^-1 (b - A x):
//   rr_{k+1} = rr_k - d_k + sum(h_* . neighbor_d)   (h_* = w_*/K baked in)
//   x_{k+1}  = x_k + d_k
//   d_{k+1}  = c1_k d_k + c2_k rr_{k+1}
// -> 8 VALU ops/point/iter, no separate z = D^-1 r step.
//
// Structure: 1 block per (batch,channel) = 84 blocks x 512 threads; thread
// owns a 2-row x 4-col patch. d double-buffered in LDS at stride 64
// (16B-aligned ds_read/write_b128, conflict-free coalesced rows). Vertical
// in-pair neighbor in-register; horizontal neighbors via __shfl lane+-1
// (wrap garbage only multiplies an exactly-zero boundary coefficient).
// One barrier per iteration, zero reductions.
// NOTE: stencil consumes only OLD d values; new values accumulate in nd[][]
// and commit after the k-loop (in-place update would corrupt left-neighbors).

#define GH 64
#define GW 64
#define GM 4096
#define NTH 512
#define NITER 20

struct ChebC { float c1[NITER]; float c2[NITER]; };
constexpr ChebC make_cheb() {
    // theta = 1.0, delta = 0.8, sigma = theta/delta = 1.25 (Saad Alg. 12.1)
    ChebC c{};
    float rho = 0.8f;                            // rho_0 = 1/sigma
    for (int k = 0; k < NITER; ++k) {
        const float rho_n = 1.0f / (2.5f - rho); // rho_{k+1} = 1/(2 sigma - rho_k)
        c.c1[k] = rho_n * rho;                   // d_{k+1} = c1*d_k + c2*rr_{k+1}
        c.c2[k] = 2.0f * rho_n / 0.8f;
        rho = rho_n;
    }
    return c;
}
constexpr ChebC CHEB = make_cheb();

__global__ __launch_bounds__(NTH) void sgc_cheb_kernel(
    const float* __restrict__ scores,   // [4,21,64,64]
    const float* __restrict__ wcol,     // [4,63,64]
    const float* __restrict__ wrow,     // [4,64,63]
    float* __restrict__ out)            // [4,21,64,64]
{
    const int blk  = blockIdx.x;             // 0..83
    const int b    = blk / 21;
    const int ch   = blk - b * 21;
    const int t    = threadIdx.x;
    const int lane = t & 63;
    const int R    = t >> 4;                 // rowpair 0..31
    const int rT   = R << 1;                 // top row of pair
    const int rB   = rT + 1;                 // bottom row of pair
    const int col0 = (t & 15) << 2;          // first owned column

    __shared__ float dbuf[2][GH][GW];        // 32 KB, stride 64 -> b128 aligned

    const float* wc = wcol + b * (63 * 64);
    const float* wr = wrow + b * (64 * 63);
    const float* bv = scores + (size_t)(b * 21 + ch) * GM;
    float*       ov = out    + (size_t)(b * 21 + ch) * GM;

    const int rowu = (rT > 0)  ? rT - 1 : 0; // halo row above (coef 0 at edge)
    const int rowd = (rB < 63) ? rB + 1 : 63;

    // Scaled stencil coefficients (reference A, then divided by diag K):
    // A[p,p]    = 1 + wc[i-1,j] + wc[i,j] + wr[i,j-1] + wr[i,j] = K
    // A[p,p-64] = -wc[i-1,j]  A[p,p+64] = -wc[i,j]
    // A[p,p-1]  = -wr[i,j-1]  A[p,p+1]  = -wr[i,j]
    // A_hat row p: 1 on diag, -w_*/K off-diag.
    float hU[2][4], hD[2][4], hL[2][4], hR[2][4], iK[2][4];
#pragma unroll
    for (int rr_ = 0; rr_ < 2; ++rr_) {
        const int i = rT + rr_;
#pragma unroll
        for (int k = 0; k < 4; ++k) {
            const int j = col0 + k;
            const float u  = (i > 0)  ? wc[(i - 1) * 64 + j] : 0.f;
            const float dn = (i < 63) ? wc[i * 64 + j]       : 0.f;
            const float l  = (j > 0)  ? wr[i * 63 + (j - 1)] : 0.f;
            const float rg = (j < 63) ? wr[i * 63 + j]       : 0.f;
            const float ik = 1.f / (1.f + u + dn + l + rg);
            iK[rr_][k] = ik;
            hU[rr_][k] = u  * ik;
            hD[rr_][k] = dn * ik;
            hL[rr_][k] = l  * ik;
            hR[rr_][k] = rg * ik;
        }
    }

    // init: x = 0, rr = D^-1 b, d = rr/theta = rr (theta = 1)
    float x[2][4], rr[2][4], d[2][4];
    const float4 bT = *reinterpret_cast<const float4*>(bv + rT * 64 + col0);
    const float4 bB = *reinterpret_cast<const float4*>(bv + rB * 64 + col0);
    const float bbT[4] = {bT.x, bT.y, bT.z, bT.w};
    const float bbB[4] = {bB.x, bB.y, bB.z, bB.w};
#pragma unroll
    for (int k = 0; k < 4; ++k) {
        x[0][k] = 0.f;  x[1][k] = 0.f;
        rr[0][k] = bbT[k] * iK[0][k];
        rr[1][k] = bbB[k] * iK[1][k];
        d[0][k] = rr[0][k];
        d[1][k] = rr[1][k];
    }
    *reinterpret_cast<float4*>(&dbuf[0][rT][col0]) =
        make_float4(d[0][0], d[0][1], d[0][2], d[0][3]);
    *reinterpret_cast<float4*>(&dbuf[0][rB][col0]) =
        make_float4(d[1][0], d[1][1], d[1][2], d[1][3]);
    __syncthreads();

    const int laneL = (lane + 63) & 63;
    const int laneR = (lane + 1) & 63;

#pragma unroll
    for (int it = 0; it < NITER; ++it) {
        const float (*rd)[GW] = dbuf[it & 1];
        float      (*wrt)[GW] = dbuf[(it + 1) & 1];

        // halo rows (neighbor rowpairs' published OLD d)
        const float4 pu4 = *reinterpret_cast<const float4*>(&rd[rowu][col0]);
        const float4 pd4 = *reinterpret_cast<const float4*>(&rd[rowd][col0]);
        const float pu[4] = {pu4.x, pu4.y, pu4.z, pu4.w};
        const float pd[4] = {pd4.x, pd4.y, pd4.z, pd4.w};

        // horizontal neighbors across lanes (wrap garbage x coef 0 at edges)
        const float plT = __shfl(d[0][3], laneL, 64);
        const float plB = __shfl(d[1][3], laneL, 64);
        const float prT = __shfl(d[0][0], laneR, 64);
        const float prB = __shfl(d[1][0], laneR, 64);

        // x += d; rr = rr - d + sum(h_* . neighbor); nd = c1*d + c2*rr
        float nd[2][4];
#pragma unroll
        for (int k = 0; k < 4; ++k) {
            const float cT = d[0][k];
            const float cB = d[1][k];
            const float lT = (k == 0) ? plT : d[0][k - 1];   // OLD d only
            const float lB = (k == 0) ? plB : d[1][k - 1];
            const float gT = (k == 3) ? prT : d[0][k + 1];
            const float gB = (k == 3) ? prB : d[1][k + 1];

            float rT_ = rr[0][k] - cT;
            rT_ = fmaf(hU[0][k], pu[k], rT_);
            rT_ = fmaf(hD[0][k], cB,   rT_);
            rT_ = fmaf(hL[0][k], lT,   rT_);
            rT_ = fmaf(hR[0][k], gT,   rT_);

            float rB_ = rr[1][k] - cB;
            rB_ = fmaf(hU[1][k], cT,   rB_);
            rB_ = fmaf(hD[1][k], pd[k], rB_);
            rB_ = fmaf(hL[1][k], lB,   rB_);
            rB_ = fmaf(hR[1][k], gB,   rB_);

            x[0][k] += cT;
            x[1][k] += cB;
            rr[0][k] = rT_;
            rr[1][k] = rB_;
            nd[0][k] = CHEB.c1[it] * cT + CHEB.c2[it] * rT_;
            nd[1][k] = CHEB.c1[it] * cB + CHEB.c2[it] * rB_;
        }
#pragma unroll
        for (int k = 0; k < 4; ++k) {        // commit after all old-d reads
            d[0][k] = nd[0][k];
            d[1][k] = nd[1][k];
        }

        *reinterpret_cast<float4*>(&wrt[rT][col0]) =
            make_float4(d[0][0], d[0][1], d[0][2], d[0][3]);
        *reinterpret_cast<float4*>(&wrt[rB][col0]) =
            make_float4(d[1][0], d[1][1], d[1][2], d[1][3]);
        __syncthreads();   // publish d_{it+1}; all reads of rd finished above
    }

    *reinterpret_cast<float4*>(ov + rT * 64 + col0) =
        make_float4(x[0][0], x[0][1], x[0][2], x[0][3]);
    *reinterpret_cast<float4*>(ov + rB * 64 + col0) =
        make_float4(x[1][0], x[1][1], x[1][2], x[1][3]);
}

extern "C" void kernel_launch(void* const* d_in, const int* in_sizes, int n_in,
                              void* d_out, int out_size, void* d_ws, size_t ws_size,
                              hipStream_t stream) {
    const float* scores = (const float*)d_in[0];  // [4,21,64,64]
    const float* wcol   = (const float*)d_in[1];  // [4,63,64]
    const float* wrow   = (const float*)d_in[2];  // [4,64,63]
    float* out = (float*)d_out;

    sgc_cheb_kernel<<<84, NTH, 0, stream>>>(scores, wcol, wrow, out);
}